// Round 6
// baseline (382714.209 us; speedup 1.0000x reference)
//
#include <hip/hip_runtime.h>
#include <math.h>

#define NWG   33
#define NT    512
#define CHOLW 32
#define DIM   256
#define LDM   260
#define TSTEPS 512
#define CLIPV 1.0e6f
#define TJIT  1.0e-4f
#define CJIT  1.0e-5f
#define MAXNLL 1.0e4f
#define LOG2PI 1.8378770664093453f

// scratch layout (float offsets into g_ws)
#define OFF_P    0
#define OFF_AP   66560
#define OFF_PP   133120
#define OFF_S    199680
#define OFF_L    266240
#define OFF_GT   332800   // 257 x 260
#define OFF_Q    399620
#define OFF_R    466180
#define OFF_VEC  532740   // mvec[256], predm[256], innov[256], gtz[256], rdiag[256], scal[...]

__device__ __align__(16) float g_ws[534276];
struct __align__(128) BarFlag { unsigned v; unsigned pad[31]; };
__device__ BarFlag g_flags[NWG];
__device__ unsigned g_broken;   // latched if a barrier ever times out (diagnostic)

// flag-array sense barrier: 1 release-store per WG + parallel polling (no serialized RMW).
// gen is monotonic across graph replays (continues from persisted flag values).
__device__ __forceinline__ void gbar(unsigned gen) {
    __syncthreads();
    if (threadIdx.x == 0) {
        __threadfence();   // release: writeback this XCD's L2
        __hip_atomic_store(&g_flags[blockIdx.x].v, gen, __ATOMIC_RELEASE, __HIP_MEMORY_SCOPE_AGENT);
    }
    if (threadIdx.x < NWG) {
        int spins = 0;
        while (__hip_atomic_load(&g_flags[threadIdx.x].v, __ATOMIC_ACQUIRE, __HIP_MEMORY_SCOPE_AGENT) < gen) {
            __builtin_amdgcn_s_sleep(1);
            if (++spins > 4000000) {
                __hip_atomic_store(&g_broken, 1u, __ATOMIC_RELAXED, __HIP_MEMORY_SCOPE_AGENT);
                break;
            }
            if ((spins & 2047) == 0 &&
                __hip_atomic_load(&g_broken, __ATOMIC_RELAXED, __HIP_MEMORY_SCOPE_AGENT) != 0u)
                break;
        }
    }
    __syncthreads();
    __threadfence();   // acquire: invalidate stale lines before reading others' data
}

__device__ __forceinline__ float fsan(float x) {
    x = isnan(x) ? 0.0f : x;
    return fminf(fmaxf(x, -CLIPV), CLIPV);
}
__device__ __forceinline__ float rdlane(float v, int l) {
    return __int_as_float(__builtin_amdgcn_readlane(__float_as_int(v), l));
}
__device__ __forceinline__ float wave_sum(float v) {
    #pragma unroll
    for (int off = 32; off; off >>= 1) v += __shfl_xor(v, off, 64);
    return v;
}

// one-wave 64x64 Cholesky reading ONLY the lower triangle of src (row stride sstride).
// lane i holds row i; column j of the trailing matrix is read from the scaled
// panel column a[j] of lane k (lower element l_kj) -- no symmetric storage needed.
__attribute__((noinline))
__device__ void chol64(const float* src, int sstride, float* Lm, float* rdiag, int b0) {
    const int lane = threadIdx.x & 63;
    float a[64];
    const float* srow = src + (size_t)lane * sstride;
    #pragma unroll
    for (int k = 0; k < 64; k += 4) {
        float4 v = *(const float4*)(srow + k);
        a[k] = v.x; a[k+1] = v.y; a[k+2] = v.z; a[k+3] = v.w;
    }
    float rdv = 0.0f;
    #pragma unroll
    for (int j = 0; j < 64; ++j) {
        float d  = rdlane(a[j], j);
        float rs = 1.0f / sqrtf(d);
        if (lane == j) rdv = rs;
        if (lane >= j) a[j] *= rs;          // a[j] = l_ij for rows i >= j
        #pragma unroll
        for (int k = j + 1; k < 64; ++k) {
            float lkj = rdlane(a[j], k);    // l_kj (lower, already scaled)
            if (lane > j) a[k] = fmaf(-a[j], lkj, a[k]);
        }
    }
    float* lrow = Lm + (size_t)(b0 + lane) * LDM + b0;
    #pragma unroll
    for (int k = 0; k < 64; k += 4) {
        float4 v; v.x = a[k]; v.y = a[k+1]; v.z = a[k+2]; v.w = a[k+3];
        *(float4*)(lrow + k) = v;
    }
    rdiag[b0 + lane] = rdv;
}

// one wave solves L[b0 diag block] x = Sm[c, b0:b0+64] (lower row of S), writes L[c, b0:b0+64].
__device__ void trsm_col_wave(const float* Sm, float* Lm, const float* rdiag, int b0, int c) {
    const int lane = threadIdx.x & 63;
    float b   = Sm[(size_t)c * LDM + b0 + lane];
    float rdl = rdiag[b0 + lane];
    float x   = 0.0f;
    const float* lbase = Lm + (size_t)(b0 + lane) * LDM + b0;
    for (int i0 = 0; i0 < 64; i0 += 4) {
        float4 lv = *(const float4*)(lbase + i0);
        #pragma unroll
        for (int s = 0; s < 4; ++s) {
            int i = i0 + s;
            float xi = rdlane(b, i) * rdlane(rdl, i);
            x = (lane == i) ? xi : x;
            float lvi = (s == 0) ? lv.x : (s == 1) ? lv.y : (s == 2) ? lv.z : lv.w;
            b = fmaf(-lvi, xi, b);   // lanes <= i corrupt their own (dead) b harmlessly
        }
    }
    Lm[(size_t)c * LDM + b0 + lane] = x;
}

// one wave: full 256 forward solve L y = rhs (rhs = PP row c == column c, or innov for c==256)
__device__ void gsolve_wave(const float* PPm, const float* innov, float* GT,
                            const float* Lm, const float* rdiag, int c) {
    const int lane = threadIdx.x & 63;
    float b[4], x[4], rd[4];
    const float* lp[4];
    #pragma unroll
    for (int q = 0; q < 4; ++q) {
        int r = lane + 64 * q;
        b[q]  = (c < 256) ? PPm[(size_t)c * LDM + r] : innov[r];
        x[q]  = 0.0f;
        rd[q] = rdiag[r];
        lp[q] = Lm + (size_t)r * LDM;
    }
    #pragma unroll
    for (int q = 0; q < 4; ++q) {             // pivot block (rows 64q..64q+63)
        for (int ii0 = 0; ii0 < 64; ii0 += 4) {
            float4 a0 = *(const float4*)(lp[0] + q * 64 + ii0);
            float4 a1 = *(const float4*)(lp[1] + q * 64 + ii0);
            float4 a2 = *(const float4*)(lp[2] + q * 64 + ii0);
            float4 a3 = *(const float4*)(lp[3] + q * 64 + ii0);
            #pragma unroll
            for (int s = 0; s < 4; ++s) {
                int il = ii0 + s;
                float xi = rdlane(b[q], il) * rdlane(rd[q], il);
                x[q] = (lane == il) ? xi : x[q];
                float c0 = (s==0)?a0.x:(s==1)?a0.y:(s==2)?a0.z:a0.w;
                float c1 = (s==0)?a1.x:(s==1)?a1.y:(s==2)?a1.z:a1.w;
                float c2 = (s==0)?a2.x:(s==1)?a2.y:(s==2)?a2.z:a2.w;
                float c3 = (s==0)?a3.x:(s==1)?a3.y:(s==2)?a3.z:a3.w;
                b[0] = fmaf(-c0, xi, b[0]);   // dead rows corrupt harmlessly
                b[1] = fmaf(-c1, xi, b[1]);
                b[2] = fmaf(-c2, xi, b[2]);
                b[3] = fmaf(-c3, xi, b[3]);
            }
        }
    }
    #pragma unroll
    for (int q = 0; q < 4; ++q) GT[(size_t)c * LDM + lane + 64 * q] = x[q];
}

// one-wave 32x32 trailing tile update: Sm[i0.., j0..] -= Lp(i0 rows) * Lp(j0 rows)^T, k=64 at col b0
__device__ void trail_tile_wave(float* Sm, const float* Lm, int i0, int j0, int b0) {
    const int lane = threadIdx.x & 63;
    const int ly = lane >> 3, lx = lane & 7;
    float acc[4][4] = {};
    for (int kk = 0; kk < 64; kk += 4) {
        float4 xv[4], yv[4];
        #pragma unroll
        for (int r = 0; r < 4; ++r)
            xv[r] = *(const float4*)(Lm + (size_t)(i0 + 4*ly + r) * LDM + b0 + kk);
        #pragma unroll
        for (int c = 0; c < 4; ++c)
            yv[c] = *(const float4*)(Lm + (size_t)(j0 + 4*lx + c) * LDM + b0 + kk);
        #pragma unroll
        for (int r = 0; r < 4; ++r)
            #pragma unroll
            for (int c = 0; c < 4; ++c) {
                acc[r][c] = fmaf(xv[r].x, yv[c].x, acc[r][c]);
                acc[r][c] = fmaf(xv[r].y, yv[c].y, acc[r][c]);
                acc[r][c] = fmaf(xv[r].z, yv[c].z, acc[r][c]);
                acc[r][c] = fmaf(xv[r].w, yv[c].w, acc[r][c]);
            }
    }
    #pragma unroll
    for (int r = 0; r < 4; ++r)
        #pragma unroll
        for (int c = 0; c < 4; ++c)
            Sm[(size_t)(i0 + 4*ly + r) * LDM + j0 + 4*lx + c] -= acc[r][c];
}

// chol WG: all lower 32-tiles of trailing region [rb, rb+32*nt)^2, panel at col b0, spread over 8 waves
__device__ void trail_panel(float* Sm, const float* Lm, int rb, int nt, int b0, int wv) {
    const int cnt = nt * (nt + 1) / 2;
    for (int idx = wv; idx < cnt; idx += 8) {
        int ti = 0, tj = 0;
        for (int a = 0, s = 0; a < nt; ++a) {
            if (idx < s + a + 1) { ti = a; tj = idx - s; break; }
            s += a + 1;
        }
        trail_tile_wave(Sm, Lm, rb + 32 * ti, rb + 32 * tj, b0);
    }
}

__global__ __launch_bounds__(NT, 2) void kf_kernel(
    const float* __restrict__ obs, const float* __restrict__ trans,
    const float* __restrict__ forc, const float* __restrict__ proc,
    const float* __restrict__ meas, const float* __restrict__ im,
    const float* __restrict__ icd, float* __restrict__ out)
{
    __shared__ float smem[8576];

    const int wg   = blockIdx.x;
    const int tid  = threadIdx.x;
    const int lane = tid & 63;
    const int wv   = tid >> 6;

    float* Pm  = g_ws + OFF_P;
    float* AP  = g_ws + OFF_AP;
    float* PPm = g_ws + OFF_PP;
    float* Sm  = g_ws + OFF_S;
    float* Lm  = g_ws + OFF_L;
    float* GT  = g_ws + OFF_GT;
    float* Qm  = g_ws + OFF_Q;
    float* Rm  = g_ws + OFF_R;
    float* vec = g_ws + OFF_VEC;
    float* mvec  = vec;
    float* predm = vec + 256;
    float* innov = vec + 512;
    float* gtz   = vec + 768;
    float* rdiag = vec + 1024;
    float* scal  = vec + 1280;   // [0]=zz, [1]=logdet, [2]=nll_sum

    float* out_filt = out + 1;
    float* out_pred = out + 1 + TSTEPS * DIM;

    unsigned gen = __hip_atomic_load(&g_flags[blockIdx.x].v, __ATOMIC_RELAXED, __HIP_MEMORY_SCOPE_AGENT);

    // ---------------- pre-phase ----------------
    for (int e = wg * NT + tid; e < DIM * DIM; e += NWG * NT) {
        int i = e >> 8, j = e & 255;
        Qm[(size_t)i * LDM + j] = 0.5f * (fsan(proc[i * 256 + j]) + fsan(proc[j * 256 + i]))
                                  + (i == j ? TJIT : 0.0f);
        Rm[(size_t)i * LDM + j] = 0.5f * (fsan(meas[i * 256 + j]) + fsan(meas[j * 256 + i]));
        Pm[(size_t)i * LDM + j] = (i == j) ? fminf(fmaxf(icd[i], 1e-6f), CLIPV) : 0.0f;
    }
    if (wg == CHOLW && tid < 256) {
        mvec[tid] = fsan(im[tid]);
        gtz[tid]  = 0.0f;
        if (tid < 3) scal[tid] = 0.0f;
    }
    gbar(++gen);

    for (int t = 0; t < TSTEPS; ++t) {
        const float* At = trans + (size_t)t * DIM * DIM;

        // ---- Ph1: AP = san(A) @ P  [WGs 0..31] | WG32: finalize t-1, then pred_m/innov ----
        if (wg < 32) {
            const int ti = wg >> 2, tj = wg & 3;
            const int i0 = ti * 32, j0 = tj * 64;
            const int ty = tid >> 5, tx = tid & 31;
            const int r0 = 2 * ty, c0 = 2 * tx;
            float a00 = 0, a01 = 0, a10 = 0, a11 = 0;
            float* As = smem;            // [32][68]
            float* Bs = smem + 32 * 68;  // [64][68]
            for (int kc = 0; kc < 256; kc += 64) {
                for (int e = tid; e < 32 * 64; e += NT) {
                    int r = e >> 6, k = e & 63;
                    As[r * 68 + k] = fsan(At[(i0 + r) * 256 + kc + k]);
                }
                for (int e = tid; e < 64 * 64; e += NT) {
                    int r = e >> 6, c = e & 63;
                    Bs[r * 68 + c] = Pm[(size_t)(kc + r) * LDM + j0 + c];
                }
                __syncthreads();
                #pragma unroll 8
                for (int k = 0; k < 64; ++k) {
                    float x0 = As[r0 * 68 + k], x1 = As[(r0 + 1) * 68 + k];
                    float y0 = Bs[k * 68 + c0], y1 = Bs[k * 68 + c0 + 1];
                    a00 = fmaf(x0, y0, a00); a01 = fmaf(x0, y1, a01);
                    a10 = fmaf(x1, y0, a10); a11 = fmaf(x1, y1, a11);
                }
                __syncthreads();
            }
            AP[(size_t)(i0 + r0) * LDM + j0 + c0]         = a00;
            AP[(size_t)(i0 + r0) * LDM + j0 + c0 + 1]     = a01;
            AP[(size_t)(i0 + r0 + 1) * LDM + j0 + c0]     = a10;
            AP[(size_t)(i0 + r0 + 1) * LDM + j0 + c0 + 1] = a11;
        } else {
            if (t > 0 && tid < 256) {
                float nm = predm[tid] + gtz[tid];
                mvec[tid] = nm;
                out_filt[(size_t)(t - 1) * DIM + tid] = nm;
                if (tid == 0) {
                    float nll = 0.5f * (scal[0] + scal[1] + 256.0f * LOG2PI);
                    scal[2] += fminf(nll, MAXNLL);
                }
            }
            __syncthreads();
            for (int r = wv * 32; r < wv * 32 + 32; ++r) {
                float s = 0.0f;
                #pragma unroll
                for (int q = 0; q < 4; ++q)
                    s = fmaf(fsan(At[(size_t)r * 256 + lane + 64 * q]), mvec[lane + 64 * q], s);
                s = wave_sum(s);
                if (lane == 0) {
                    float pm = s + fsan(forc[(size_t)t * DIM + r]);
                    predm[r] = pm;
                    innov[r] = obs[(size_t)t * DIM + r] - pm;
                    out_pred[(size_t)t * DIM + r] = pm;
                }
            }
        }
        gbar(++gen);

        // ---- Ph2: lower 32-tiles of sym(A P A^T): PP (full, mirrored) and S (lower) ----
        for (int idx = wg; idx < 36; idx += NWG) {
            int ti = 0, tj = 0;
            for (int a = 0, s = 0; a < 8; ++a) {
                if (idx < s + a + 1) { ti = a; tj = idx - s; break; }
                s += a + 1;
            }
            const int i0 = 32 * ti, j0 = 32 * tj;
            const int ty = tid >> 5, tx = tid & 31;
            const int r0 = 2 * ty;
            float acc1_0 = 0, acc1_1 = 0, acc2_0 = 0, acc2_1 = 0;
            float* APi = smem;               // [32][67]
            float* Aj  = smem + 32 * 67;
            float* Ai  = smem + 2 * 32 * 67;
            float* APj = smem + 3 * 32 * 67;
            for (int kc = 0; kc < 256; kc += 64) {
                for (int e = tid; e < 32 * 64; e += NT) {
                    int r = e >> 6, k = e & 63;
                    APi[r * 67 + k] = AP[(size_t)(i0 + r) * LDM + kc + k];
                    Aj [r * 67 + k] = fsan(At[(j0 + r) * 256 + kc + k]);
                    Ai [r * 67 + k] = fsan(At[(i0 + r) * 256 + kc + k]);
                    APj[r * 67 + k] = AP[(size_t)(j0 + r) * LDM + kc + k];
                }
                __syncthreads();
                #pragma unroll 4
                for (int k = 0; k < 64; ++k) {
                    float aj  = Aj [tx * 67 + k];
                    float apj = APj[tx * 67 + k];
                    float x0 = APi[r0 * 67 + k], x1 = APi[(r0 + 1) * 67 + k];
                    float w0 = Ai [r0 * 67 + k], w1 = Ai [(r0 + 1) * 67 + k];
                    acc1_0 = fmaf(x0, aj,  acc1_0); acc1_1 = fmaf(x1, aj,  acc1_1);
                    acc2_0 = fmaf(w0, apj, acc2_0); acc2_1 = fmaf(w1, apj, acc2_1);
                }
                __syncthreads();
            }
            #pragma unroll
            for (int r = 0; r < 2; ++r) {
                int gi = i0 + r0 + r, gj = j0 + tx;
                float sym = 0.5f * ((r == 0 ? acc1_0 : acc1_1) + (r == 0 ? acc2_0 : acc2_1));
                float pp  = sym + Qm[(size_t)gi * LDM + gj];
                PPm[(size_t)gi * LDM + gj] = pp;
                PPm[(size_t)gj * LDM + gi] = pp;
                if (gi >= gj)
                    Sm[(size_t)gi * LDM + gj] = pp + Rm[(size_t)gi * LDM + gj]
                                                + (gi == gj ? CJIT : 0.0f);
            }
        }
        gbar(++gen);

        // ---- Ph3: full 256x256 Cholesky by WG32 alone (lower-only, internal syncs) ----
        if (wg == CHOLW) {
            if (wv == 0) chol64(Sm, LDM, Lm, rdiag, 0);
            __syncthreads();
            for (int c = 64 + wv; c < 256; c += 8) trsm_col_wave(Sm, Lm, rdiag, 0, c);
            __syncthreads();
            trail_panel(Sm, Lm, 64, 6, 0, wv);
            __syncthreads();
            if (wv == 0) chol64(Sm + (size_t)64 * LDM + 64, LDM, Lm, rdiag, 64);
            __syncthreads();
            for (int c = 128 + wv; c < 256; c += 8) trsm_col_wave(Sm, Lm, rdiag, 64, c);
            __syncthreads();
            trail_panel(Sm, Lm, 128, 4, 64, wv);
            __syncthreads();
            if (wv == 0) chol64(Sm + (size_t)128 * LDM + 128, LDM, Lm, rdiag, 128);
            __syncthreads();
            for (int c = 192 + wv; c < 256; c += 8) trsm_col_wave(Sm, Lm, rdiag, 128, c);
            __syncthreads();
            trail_panel(Sm, Lm, 192, 2, 128, wv);
            __syncthreads();
            if (wv == 0) chol64(Sm + (size_t)192 * LDM + 192, LDM, Lm, rdiag, 192);
        }
        gbar(++gen);

        // ---- Ph4: G = L^{-1}[PP | innov]  (257 wave-parallel column solves) ----
        {
            int c = wg * 8 + wv;
            if (c < 257) gsolve_wave(PPm, innov, GT, Lm, rdiag, c);
        }
        gbar(++gen);

        // ---- Ph5: newP = PP - G^T G (lower tiles + mirror) | WG32: gtz, zz, logdet ----
        if (wg < 32) {
            for (int idx = wg; idx < 36; idx += 32) {
                int ti = 0, tj = 0;
                for (int a = 0, s = 0; a < 8; ++a) {
                    if (idx < s + a + 1) { ti = a; tj = idx - s; break; }
                    s += a + 1;
                }
                const int i0 = 32 * ti, j0 = 32 * tj;
                const int ty = tid >> 5, tx = tid & 31;
                const int r0 = 2 * ty;
                float acc0 = 0, acc1 = 0;
                float* GTi = smem;            // [32][67]
                float* GTj = smem + 32 * 67;
                for (int kc = 0; kc < 256; kc += 64) {
                    for (int e = tid; e < 32 * 64; e += NT) {
                        int r = e >> 6, k = e & 63;
                        GTi[r * 67 + k] = GT[(size_t)(i0 + r) * LDM + kc + k];
                        GTj[r * 67 + k] = GT[(size_t)(j0 + r) * LDM + kc + k];
                    }
                    __syncthreads();
                    #pragma unroll 4
                    for (int k = 0; k < 64; ++k) {
                        float gj = GTj[tx * 67 + k];
                        acc0 = fmaf(GTi[r0 * 67 + k],       gj, acc0);
                        acc1 = fmaf(GTi[(r0 + 1) * 67 + k], gj, acc1);
                    }
                    __syncthreads();
                }
                #pragma unroll
                for (int r = 0; r < 2; ++r) {
                    int gi = i0 + r0 + r, gj = j0 + tx;
                    float v = PPm[(size_t)gi * LDM + gj] - (r == 0 ? acc0 : acc1);
                    Pm[(size_t)gi * LDM + gj] = v;
                    Pm[(size_t)gj * LDM + gi] = v;
                }
            }
        } else {
            const float* zrow = GT + (size_t)256 * LDM;
            for (int r = wv * 32; r < wv * 32 + 32; ++r) {
                float s = 0.0f;
                #pragma unroll
                for (int q = 0; q < 4; ++q)
                    s = fmaf(GT[(size_t)r * LDM + lane + 64 * q], zrow[lane + 64 * q], s);
                s = wave_sum(s);
                if (lane == 0) gtz[r] = s;
            }
            if (wv == 0) {
                float s = 0.0f;
                #pragma unroll
                for (int q = 0; q < 4; ++q) {
                    float z = zrow[lane + 64 * q];
                    s = fmaf(z, z, s);
                }
                s = wave_sum(s);
                if (lane == 0) scal[0] = s;
            } else if (wv == 1) {
                float s = 0.0f;
                #pragma unroll
                for (int q = 0; q < 4; ++q) s += logf(rdiag[lane + 64 * q]);
                s = wave_sum(s);
                if (lane == 0) scal[1] = -2.0f * s;   // logdet = 2*sum(log L_ii)
            }
        }
        gbar(++gen);
    }

    // ---------------- post: finalize t = 511 ----------------
    if (wg == CHOLW && tid < 256) {
        float nm = predm[tid] + gtz[tid];
        out_filt[(size_t)511 * DIM + tid] = nm;
        if (tid == 0) {
            float nll = fminf(0.5f * (scal[0] + scal[1] + 256.0f * LOG2PI), MAXNLL);
            out[0] = scal[2] + nll;
            if (__hip_atomic_load(&g_broken, __ATOMIC_RELAXED, __HIP_MEMORY_SCOPE_AGENT) != 0u)
                out[0] = -1.2345678e7f;   // sentinel: barrier timed out
        }
    }
}

extern "C" void kernel_launch(void* const* d_in, const int* in_sizes, int n_in,
                              void* d_out, int out_size, void* d_ws, size_t ws_size,
                              hipStream_t stream) {
    (void)in_sizes; (void)n_in; (void)out_size; (void)d_ws; (void)ws_size;
    const float* obs  = (const float*)d_in[0];
    const float* trn  = (const float*)d_in[1];
    const float* forc = (const float*)d_in[2];
    const float* proc = (const float*)d_in[3];
    const float* meas = (const float*)d_in[4];
    const float* im   = (const float*)d_in[5];
    const float* icd  = (const float*)d_in[6];
    float* out = (float*)d_out;

    kf_kernel<<<dim3(NWG), dim3(NT), 0, stream>>>(obs, trn, forc, proc, meas, im, icd, out);
}